// Round 6
// baseline (8280.473 us; speedup 1.0000x reference)
//
#include <hip/hip_runtime.h>
#include <hip/hip_bf16.h>

#define SEQ_LEN 256
#define HIDDEN  2048
#define CLASSES 10
#define BATCH   128
#define NWG     256
#define WG_THREADS 512
#define STEPS   (SEQ_LEN - 1)
#define KTILES  64            // 2048 / 32

typedef __attribute__((ext_vector_type(8))) short  bf16x8;
typedef __attribute__((ext_vector_type(8))) unsigned short u16x8;
typedef __attribute__((ext_vector_type(4))) float  f32x4;
typedef __attribute__((ext_vector_type(4))) unsigned int u32x4;

// ---- workspace layout (bytes) ----
#define WHP_OFF  0
#define HB_OFF   33554432UL                    // 4 x 512 KB rotating h buffers
#define HF_OFF   (HB_OFF + 4UL * 524288UL)     // fp32 h_final [128][2048]
#define BAR_OFF  (HF_OFF + 1048576UL)
// bar layout (dwords):
//   [0..255]          arrival slot per WG (posted stores; leader L polls [32L..32L+32))
//   [512 + 16*L]      done[L], L=0..7 (64B apart)
//   [1024 + 16*j]     release line j, j=0..31 (64B apart; WG polls j = W & 31)

__device__ __forceinline__ unsigned short f2bf(float f) {
    unsigned int u = __float_as_uint(f);
    return (unsigned short)((u + 0x7FFFu + ((u >> 16) & 1u)) >> 16);
}
__device__ __forceinline__ float sigm(float z)  { return 1.0f / (1.0f + __expf(-z)); }
__device__ __forceinline__ float tanh_f(float z){ return 2.0f / (1.0f + __expf(-2.0f * z)) - 1.0f; }

__device__ __forceinline__ unsigned int aload(const unsigned int* p) {
    return __hip_atomic_load(p, __ATOMIC_RELAXED, __HIP_MEMORY_SCOPE_AGENT);
}
__device__ __forceinline__ void astore(unsigned int* p, unsigned int v) {
    __hip_atomic_store(p, v, __ATOMIC_RELAXED, __HIP_MEMORY_SCOPE_AGENT);
}
// L2-bypassing (agent-coherent, sc1) 8-byte load: reads h straight from the
// L3 coherence point -> no inv ever needed, no L2-MSHR fill serialization.
__device__ __forceinline__ unsigned long long aload64(const unsigned long long* p) {
    return __hip_atomic_load(p, __ATOMIC_RELAXED, __HIP_MEMORY_SCOPE_AGENT);
}
__device__ __forceinline__ bf16x8 pack_frag(unsigned long long lo, unsigned long long hi) {
    union { unsigned long long q[2]; bf16x8 v; } u;
    u.q[0] = lo; u.q[1] = hi;
    return u.v;
}

// Pack Wh [2048][8192] fp32 -> bf16 in exact MFMA B-fragment order (see R1 notes).
__global__ void lstm_pack_kernel(const float* __restrict__ Wh,
                                 unsigned short* __restrict__ whp,
                                 unsigned short* __restrict__ hbufs,
                                 unsigned int* __restrict__ bar) {
    int chunk = blockIdx.x * 256 + threadIdx.x;     // 2,097,152 chunks total
    int lane = chunk & 63;
    int nt   = (chunk >> 6) & 1;
    int kt   = (chunk >> 7) & 63;
    int W    = chunk >> 13;
    int q = lane >> 4, l16 = lane & 15;
    int c32  = nt * 16 + l16;
    int gate = c32 >> 3, u = c32 & 7;
    int n    = gate * 2048 + W * 8 + u;
    int k0   = kt * 32 + q * 8;
    u16x8 frag;
    #pragma unroll
    for (int j = 0; j < 8; ++j)
        frag[j] = f2bf(Wh[(size_t)(k0 + j) * 8192 + n]);
    ((u16x8*)whp)[chunk] = frag;

    if (chunk < 32768) ((u32x4*)hbufs)[chunk] = (u32x4){0, 0, 0, 0};   // buf0: h(0)=0
    if (chunk < 2048) bar[chunk] = 0u;                                 // barrier words
}

// Contention-free monotonic barrier (phase = t+1, never reset).
// h stores are sc1 write-through (drained by the first __syncthreads before
// the arrival store); h LOADS are sc1 too -> no release fence AND no acquire
// fence needed for h. do_inv only protects the final cached-epilogue handoff.
__device__ __forceinline__ void grid_barrier(unsigned int* bar, unsigned int phase,
                                             bool do_inv, int W) {
    __syncthreads();   // drain sc1 h stores to the coherence point
    if (threadIdx.x < 64) {
        const int lane = threadIdx.x;
        if (lane == 0) astore(&bar[W], phase);                 // arrival
        if (W < 8) {
            unsigned int* sl = &bar[W * 32 + (lane & 31)];
            while (!__all((int)(aload(sl) >= phase)))
                __builtin_amdgcn_s_sleep(1);
            if (lane == 0) astore(&bar[512 + 16 * W], phase);  // done[W]
            if (W == 0) {
                unsigned int* dn = &bar[512 + 16 * (lane & 7)];
                while (!__all((int)(aload(dn) >= phase)))
                    __builtin_amdgcn_s_sleep(1);
                if (lane < 32) astore(&bar[1024 + 16 * lane], phase);  // broadcast
            }
        }
        if (lane == 0 && W != 0) {
            unsigned int* rl = &bar[1024 + 16 * (W & 31)];
            while (aload(rl) < phase)
                __builtin_amdgcn_s_sleep(1);
        }
        if (do_inv)
            __builtin_amdgcn_fence(__ATOMIC_ACQUIRE, "agent");   // buffer_inv (L1+L2)
    }
    __syncthreads();
}

__global__ __launch_bounds__(WG_THREADS, 2) void lstm_persist(
    const float* __restrict__ x,  const float* __restrict__ Wx,
    const float* __restrict__ b,  const float* __restrict__ Wph,
    const float* __restrict__ bp, const unsigned short* __restrict__ whp,
    unsigned short* hbufs, float* hfin,
    unsigned int* bar, float* out)
{
    extern __shared__ char lds[];
    const int tid = threadIdx.x;
    const int W   = blockIdx.x;

    // stage this WG's Wh slice (128 KB) into LDS
    {
        const u32x4* src = (const u32x4*)whp + (size_t)W * 8192;
        u32x4* dst = (u32x4*)lds;
        for (int i = tid; i < 8192; i += WG_THREADS) dst[i] = src[i];
    }
    __syncthreads();

    const int lane = tid & 63;
    const int wv   = tid >> 6;          // wave 0..7 -> M-tile
    const int q    = lane >> 4;         // quad 0..3
    const int l16  = lane & 15;
    const int s    = (lane >> 3) & 1;   // 0: holds (g,f); 1: holds (i,o)
    const int u    = lane & 7;          // hidden unit within slice
    const int rowA = wv * 16 + l16;     // A row this lane loads
    const int row0 = wv * 16 + q * 4;   // C/D rows row0..row0+3
    const int colh = W * 8 + u;         // global hidden index this lane updates

    const int n0 = ((l16) >> 3) * 2048 + W * 8 + (l16 & 7);
    const int n1 = ((16 + l16) >> 3) * 2048 + W * 8 + ((16 + l16) & 7);
    const float wx0 = Wx[n0], bb0 = b[n0];
    const float wx1 = Wx[n1], bb1 = b[n1];

    // A-fragment base in u64 units: row stride = 512 u64, quad offset = 2 u64
    const int aBase = rowA * 512 + q * 2;

    float c_state[4] = {0.f, 0.f, 0.f, 0.f};

    for (int t = 0; t < STEPS; ++t) {
        unsigned short* hcur  = hbufs + (size_t)(t & 3) * 262144;        // elements
        unsigned short* hnext = hbufs + (size_t)((t + 1) & 3) * 262144;

        const unsigned long long* au = (const unsigned long long*)hcur;
        const char* lp = lds + lane * 16;

        // ring-3 software pipeline: blocks of 8 kt, 2 blocks of sc1 loads in flight
        bf16x8 afr[3][8];
        #pragma unroll
        for (int j = 0; j < 8; ++j) {
            afr[0][j] = pack_frag(aload64(&au[aBase + j * 8]),
                                  aload64(&au[aBase + j * 8 + 1]));
        }
        #pragma unroll
        for (int j = 0; j < 8; ++j) {
            afr[1][j] = pack_frag(aload64(&au[aBase + (8 + j) * 8]),
                                  aload64(&au[aBase + (8 + j) * 8 + 1]));
        }

        float xv[4];
        #pragma unroll
        for (int r = 0; r < 4; ++r) xv[r] = x[(row0 + r) * SEQ_LEN + t];

        f32x4 acc0 = {0.f, 0.f, 0.f, 0.f};
        f32x4 acc1 = {0.f, 0.f, 0.f, 0.f};
        #pragma unroll
        for (int blk = 0; blk < 8; ++blk) {
            if (blk < 6) {
                #pragma unroll
                for (int j = 0; j < 8; ++j) {
                    const int kt = (blk + 2) * 8 + j;
                    afr[(blk + 2) % 3][j] = pack_frag(aload64(&au[aBase + kt * 8]),
                                                      aload64(&au[aBase + kt * 8 + 1]));
                }
            }
            #pragma unroll
            for (int j = 0; j < 8; ++j) {
                const int kt = blk * 8 + j;
                bf16x8 b0 = *(const bf16x8*)(lp + (kt * 2 + 0) * 1024);
                bf16x8 b1 = *(const bf16x8*)(lp + (kt * 2 + 1) * 1024);
                acc0 = __builtin_amdgcn_mfma_f32_16x16x32_bf16(afr[blk % 3][j], b0, acc0, 0, 0, 0);
                acc1 = __builtin_amdgcn_mfma_f32_16x16x32_bf16(afr[blk % 3][j], b1, acc1, 0, 0, 0);
            }
        }

        const bool last = (t == STEPS - 1);
        #pragma unroll
        for (int r = 0; r < 4; ++r) {
            float z0 = acc0[r] + xv[r] * wx0 + bb0;
            float z1 = acc1[r] + xv[r] * wx1 + bb1;
            float p0 = __shfl_xor(z0, 8, 64);
            float p1 = __shfl_xor(z1, 8, 64);
            float zg = s ? p0 : z0;
            float zi = s ? z0 : p0;
            float zf = s ? p1 : z1;
            float zo = s ? z1 : p1;
            float cn = tanh_f(zg) * sigm(zi) + c_state[r] * sigm(zf);
            c_state[r] = cn;
            float h = tanh_f(cn) * sigm(zo);
            // lanes u and u^1 hold adjacent columns (same rows); pack 2 bf16 -> 4B
            float hn = __shfl_xor(h, 1, 64);
            int row = row0 + r;
            if ((lane & 9) == 0) {   // s==0 && u even
                unsigned int packed = (unsigned int)f2bf(h)
                                    | ((unsigned int)f2bf(hn) << 16);
                astore((unsigned int*)&hnext[row * HIDDEN + colh], packed);
            }
            if (last && s == 0) {
                __hip_atomic_store(&hfin[row * HIDDEN + colh], h,
                                   __ATOMIC_RELAXED, __HIP_MEMORY_SCOPE_AGENT);
            }
        }
        // h needs no inv (sc1 reads); the single last-step inv protects the
        // epilogue's cached hfin/Wph reads from stale/poisoned L2 lines.
        grid_barrier(bar, (unsigned int)(t + 1), last, W);
    }

    // ---- classifier + softmax epilogue: WG b handles batch row b ----
    if (W < BATCH) {
        float part[CLASSES];
        #pragma unroll
        for (int c = 0; c < CLASSES; ++c) part[c] = 0.f;
        for (int k = tid; k < HIDDEN; k += WG_THREADS) {
            float hv = hfin[W * HIDDEN + k];
            #pragma unroll
            for (int c = 0; c < CLASSES; ++c) part[c] += hv * Wph[k * CLASSES + c];
        }
        #pragma unroll
        for (int c = 0; c < CLASSES; ++c)
            for (int off = 32; off > 0; off >>= 1)
                part[c] += __shfl_xor(part[c], off, 64);
        float* red = (float*)lds;
        __syncthreads();
        if (lane == 0)
            for (int c = 0; c < CLASSES; ++c) red[wv * CLASSES + c] = part[c];
        __syncthreads();
        if (tid == 0) {
            float lg[CLASSES];
            for (int c = 0; c < CLASSES; ++c) {
                float sm = bp[c];
                for (int w8 = 0; w8 < 8; ++w8) sm += red[w8 * CLASSES + c];
                lg[c] = sm;
            }
            float mx = lg[0];
            for (int c = 1; c < CLASSES; ++c) mx = fmaxf(mx, lg[c]);
            float se = 0.f;
            for (int c = 0; c < CLASSES; ++c) { lg[c] = __expf(lg[c] - mx); se += lg[c]; }
            float inv = 1.0f / se;
            for (int c = 0; c < CLASSES; ++c) out[W * CLASSES + c] = lg[c] * inv;
        }
    }
}

extern "C" void kernel_launch(void* const* d_in, const int* in_sizes, int n_in,
                              void* d_out, int out_size, void* d_ws, size_t ws_size,
                              hipStream_t stream) {
    const float* x   = (const float*)d_in[0];
    const float* Wx  = (const float*)d_in[1];
    const float* Wh  = (const float*)d_in[2];
    const float* b   = (const float*)d_in[3];
    const float* Wph = (const float*)d_in[4];
    const float* bp  = (const float*)d_in[5];
    float* out = (float*)d_out;

    char* ws = (char*)d_ws;
    unsigned short* whp  = (unsigned short*)(ws + WHP_OFF);
    unsigned short* hbufs= (unsigned short*)(ws + HB_OFF);
    float*          hfin = (float*)(ws + HF_OFF);
    unsigned int*   bar  = (unsigned int*)(ws + BAR_OFF);

    hipFuncSetAttribute((const void*)lstm_persist,
                        hipFuncAttributeMaxDynamicSharedMemorySize, 131072);

    lstm_pack_kernel<<<8192, 256, 0, stream>>>(Wh, whp, hbufs, bar);
    lstm_persist<<<NWG, WG_THREADS, 131072, stream>>>(x, Wx, b, Wph, bp,
                                                      whp, hbufs, hfin, bar, out);
}

// Round 7
// 4967.364 us; speedup vs baseline: 1.6670x; 1.6670x over previous
//
#include <hip/hip_runtime.h>
#include <hip/hip_bf16.h>

#define SEQ_LEN 256
#define HIDDEN  2048
#define CLASSES 10
#define BATCH   128
#define NWG     256
#define WG_THREADS 512
#define STEPS   (SEQ_LEN - 1)
#define KTILES  64            // 2048 / 32

typedef __attribute__((ext_vector_type(8))) short  bf16x8;
typedef __attribute__((ext_vector_type(8))) unsigned short u16x8;
typedef __attribute__((ext_vector_type(4))) float  f32x4;
typedef __attribute__((ext_vector_type(4))) unsigned int u32x4;

// ---- workspace layout (bytes) ----
#define WHP_OFF  0
#define HB_OFF   33554432UL                    // 4 x 512 KB rotating h buffers
#define HF_OFF   (HB_OFF + 4UL * 524288UL)     // fp32 h_final [128][2048]
#define BAR_OFF  (HF_OFF + 1048576UL)
// bar layout (dwords):
//   [0..255]          arrival slot per WG (posted stores; leader L polls [32L..32L+32))
//   [512 + 16*L]      done[L], L=0..7 (64B apart)
//   [1024 + 16*j]     release line j, j=0..31 (64B apart; WG polls j = W & 31)

__device__ __forceinline__ unsigned short f2bf(float f) {
    unsigned int u = __float_as_uint(f);
    return (unsigned short)((u + 0x7FFFu + ((u >> 16) & 1u)) >> 16);
}
__device__ __forceinline__ float sigm(float z)  { return 1.0f / (1.0f + __expf(-z)); }
__device__ __forceinline__ float tanh_f(float z){ return 2.0f / (1.0f + __expf(-2.0f * z)) - 1.0f; }

__device__ __forceinline__ unsigned int aload(const unsigned int* p) {
    return __hip_atomic_load(p, __ATOMIC_RELAXED, __HIP_MEMORY_SCOPE_AGENT);
}
__device__ __forceinline__ void astore(unsigned int* p, unsigned int v) {
    __hip_atomic_store(p, v, __ATOMIC_RELAXED, __HIP_MEMORY_SCOPE_AGENT);
}

// Pack Wh [2048][8192] fp32 -> bf16 in exact MFMA B-fragment order (see R1 notes).
__global__ void lstm_pack_kernel(const float* __restrict__ Wh,
                                 unsigned short* __restrict__ whp,
                                 unsigned short* __restrict__ hbufs,
                                 unsigned int* __restrict__ bar) {
    int chunk = blockIdx.x * 256 + threadIdx.x;     // 2,097,152 chunks total
    int lane = chunk & 63;
    int nt   = (chunk >> 6) & 1;
    int kt   = (chunk >> 7) & 63;
    int W    = chunk >> 13;
    int q = lane >> 4, l16 = lane & 15;
    int c32  = nt * 16 + l16;
    int gate = c32 >> 3, u = c32 & 7;
    int n    = gate * 2048 + W * 8 + u;
    int k0   = kt * 32 + q * 8;
    u16x8 frag;
    #pragma unroll
    for (int j = 0; j < 8; ++j)
        frag[j] = f2bf(Wh[(size_t)(k0 + j) * 8192 + n]);
    ((u16x8*)whp)[chunk] = frag;

    if (chunk < 32768) ((u32x4*)hbufs)[chunk] = (u32x4){0, 0, 0, 0};   // buf0: h(0)=0
    if (chunk < 2048) bar[chunk] = 0u;                                 // barrier words
}

// Contention-free monotonic barrier (phase = t+1, never reset).
// h stores are sc1 write-through, drained by the first __syncthreads before the
// arrival store -> release ordering with no wbl2. Acquire inv only when do_inv.
__device__ __forceinline__ void grid_barrier(unsigned int* bar, unsigned int phase,
                                             bool do_inv, int W) {
    __syncthreads();   // drain sc1 h stores to the coherence point
    if (threadIdx.x < 64) {
        const int lane = threadIdx.x;
        if (lane == 0) astore(&bar[W], phase);                 // arrival
        if (W < 8) {
            unsigned int* sl = &bar[W * 32 + (lane & 31)];
            while (!__all((int)(aload(sl) >= phase)))
                __builtin_amdgcn_s_sleep(1);
            if (lane == 0) astore(&bar[512 + 16 * W], phase);  // done[W]
            if (W == 0) {
                unsigned int* dn = &bar[512 + 16 * (lane & 7)];
                while (!__all((int)(aload(dn) >= phase)))
                    __builtin_amdgcn_s_sleep(1);
                if (lane < 32) astore(&bar[1024 + 16 * lane], phase);  // broadcast
            }
        }
        if (lane == 0 && W != 0) {
            unsigned int* rl = &bar[1024 + 16 * (W & 31)];
            while (aload(rl) < phase)
                __builtin_amdgcn_s_sleep(1);
        }
        if (do_inv)
            __builtin_amdgcn_fence(__ATOMIC_ACQUIRE, "agent");   // buffer_inv (L1+L2)
    }
    __syncthreads();
}

__global__ __launch_bounds__(WG_THREADS, 2) void lstm_persist(
    const float* __restrict__ x,  const float* __restrict__ Wx,
    const float* __restrict__ b,  const float* __restrict__ Wph,
    const float* __restrict__ bp, const unsigned short* __restrict__ whp,
    unsigned short* hbufs, float* hfin,
    unsigned int* bar, float* out)
{
    extern __shared__ char lds[];
    const int tid = threadIdx.x;
    const int W   = blockIdx.x;

    // stage this WG's Wh slice (128 KB) into LDS
    {
        const u32x4* src = (const u32x4*)whp + (size_t)W * 8192;
        u32x4* dst = (u32x4*)lds;
        for (int i = tid; i < 8192; i += WG_THREADS) dst[i] = src[i];
    }
    __syncthreads();

    const int lane = tid & 63;
    const int wv   = tid >> 6;          // wave 0..7 -> M-tile
    const int q    = lane >> 4;         // quad 0..3
    const int l16  = lane & 15;
    const int s    = (lane >> 3) & 1;   // 0: holds (g,f); 1: holds (i,o)
    const int u    = lane & 7;          // hidden unit within slice
    const int rowA = wv * 16 + l16;     // A row this lane loads
    const int row0 = wv * 16 + q * 4;   // C/D rows row0..row0+3
    const int colh = W * 8 + u;         // global hidden index this lane updates

    const int n0 = ((l16) >> 3) * 2048 + W * 8 + (l16 & 7);
    const int n1 = ((16 + l16) >> 3) * 2048 + W * 8 + ((16 + l16) & 7);
    const float wx0 = Wx[n0], bb0 = b[n0];
    const float wx1 = Wx[n1], bb1 = b[n1];

    // K-sweep stagger: CUs within an XCD (W>>3 under the %8 XCD round-robin)
    // start at 32 distinct kt positions -> their L2 demand-miss sets are
    // DISJOINT lines, multiplying the XCD's distinct outstanding misses ~32x
    // so the post-barrier 512 KB refill runs bandwidth- not latency-bound.
    const int ktoff = ((W >> 3) & 31) * 2;

    float c_state[4] = {0.f, 0.f, 0.f, 0.f};

    for (int t = 0; t < STEPS; ++t) {
        unsigned short* hcur  = hbufs + (size_t)(t & 3) * 262144;        // elements
        unsigned short* hnext = hbufs + (size_t)((t + 1) & 3) * 262144;

        const bf16x8* ap = (const bf16x8*)hcur + rowA * 256 + q;   // 256 chunks/row
        const char* lp = lds + lane * 16;

        float xv[4];
        #pragma unroll
        for (int r = 0; r < 4; ++r) xv[r] = x[(row0 + r) * SEQ_LEN + t];

        f32x4 acc0 = {0.f, 0.f, 0.f, 0.f};
        f32x4 acc1 = {0.f, 0.f, 0.f, 0.f};
        int kt = ktoff;
        bf16x8 a_cur = ap[kt * 4];
        #pragma unroll 8
        for (int i = 0; i < KTILES; ++i) {
            const int ktn = (kt + 1) & 63;
            bf16x8 a_nxt = ap[ktn * 4];                  // depth-1 prefetch
            bf16x8 b0 = *(const bf16x8*)(lp + (kt * 2 + 0) * 1024);
            bf16x8 b1 = *(const bf16x8*)(lp + (kt * 2 + 1) * 1024);
            acc0 = __builtin_amdgcn_mfma_f32_16x16x32_bf16(a_cur, b0, acc0, 0, 0, 0);
            acc1 = __builtin_amdgcn_mfma_f32_16x16x32_bf16(a_cur, b1, acc1, 0, 0, 0);
            a_cur = a_nxt;
            kt = ktn;
        }

        const bool last = (t == STEPS - 1);
        #pragma unroll
        for (int r = 0; r < 4; ++r) {
            float z0 = acc0[r] + xv[r] * wx0 + bb0;
            float z1 = acc1[r] + xv[r] * wx1 + bb1;
            float p0 = __shfl_xor(z0, 8, 64);
            float p1 = __shfl_xor(z1, 8, 64);
            float zg = s ? p0 : z0;
            float zi = s ? z0 : p0;
            float zf = s ? p1 : z1;
            float zo = s ? z1 : p1;
            float cn = tanh_f(zg) * sigm(zi) + c_state[r] * sigm(zf);
            c_state[r] = cn;
            float h = tanh_f(cn) * sigm(zo);
            // lanes u and u^1 hold adjacent columns (same rows); pack 2 bf16 -> 4B
            float hn = __shfl_xor(h, 1, 64);
            int row = row0 + r;
            if ((lane & 9) == 0) {   // s==0 && u even
                unsigned int packed = (unsigned int)f2bf(h)
                                    | ((unsigned int)f2bf(hn) << 16);
                astore((unsigned int*)&hnext[row * HIDDEN + colh], packed);
            }
            if (last && s == 0) {
                __hip_atomic_store(&hfin[row * HIDDEN + colh], h,
                                   __ATOMIC_RELAXED, __HIP_MEMORY_SCOPE_AGENT);
            }
        }
        // inv every 4th barrier (stale L2 age <= 4 with the 4-buffer rotation);
        // t==254 (phase 2) also covers the hfin handoff to the cached epilogue.
        grid_barrier(bar, (unsigned int)(t + 1), (t & 3) == 2 || last, W);
    }

    // ---- classifier + softmax epilogue: WG b handles batch row b ----
    if (W < BATCH) {
        float part[CLASSES];
        #pragma unroll
        for (int c = 0; c < CLASSES; ++c) part[c] = 0.f;
        for (int k = tid; k < HIDDEN; k += WG_THREADS) {
            float hv = hfin[W * HIDDEN + k];
            #pragma unroll
            for (int c = 0; c < CLASSES; ++c) part[c] += hv * Wph[k * CLASSES + c];
        }
        #pragma unroll
        for (int c = 0; c < CLASSES; ++c)
            for (int off = 32; off > 0; off >>= 1)
                part[c] += __shfl_xor(part[c], off, 64);
        float* red = (float*)lds;
        __syncthreads();
        if (lane == 0)
            for (int c = 0; c < CLASSES; ++c) red[wv * CLASSES + c] = part[c];
        __syncthreads();
        if (tid == 0) {
            float lg[CLASSES];
            for (int c = 0; c < CLASSES; ++c) {
                float sm = bp[c];
                for (int w8 = 0; w8 < 8; ++w8) sm += red[w8 * CLASSES + c];
                lg[c] = sm;
            }
            float mx = lg[0];
            for (int c = 1; c < CLASSES; ++c) mx = fmaxf(mx, lg[c]);
            float se = 0.f;
            for (int c = 0; c < CLASSES; ++c) { lg[c] = __expf(lg[c] - mx); se += lg[c]; }
            float inv = 1.0f / se;
            for (int c = 0; c < CLASSES; ++c) out[W * CLASSES + c] = lg[c] * inv;
        }
    }
}

extern "C" void kernel_launch(void* const* d_in, const int* in_sizes, int n_in,
                              void* d_out, int out_size, void* d_ws, size_t ws_size,
                              hipStream_t stream) {
    const float* x   = (const float*)d_in[0];
    const float* Wx  = (const float*)d_in[1];
    const float* Wh  = (const float*)d_in[2];
    const float* b   = (const float*)d_in[3];
    const float* Wph = (const float*)d_in[4];
    const float* bp  = (const float*)d_in[5];
    float* out = (float*)d_out;

    char* ws = (char*)d_ws;
    unsigned short* whp  = (unsigned short*)(ws + WHP_OFF);
    unsigned short* hbufs= (unsigned short*)(ws + HB_OFF);
    float*          hfin = (float*)(ws + HF_OFF);
    unsigned int*   bar  = (unsigned int*)(ws + BAR_OFF);

    hipFuncSetAttribute((const void*)lstm_persist,
                        hipFuncAttributeMaxDynamicSharedMemorySize, 131072);

    lstm_pack_kernel<<<8192, 256, 0, stream>>>(Wh, whp, hbufs, bar);
    lstm_persist<<<NWG, WG_THREADS, 131072, stream>>>(x, Wx, b, Wph, bp,
                                                      whp, hbufs, hfin, bar, out);
}

// Round 8
// 2647.210 us; speedup vs baseline: 3.1280x; 1.8765x over previous
//
#include <hip/hip_runtime.h>
#include <hip/hip_bf16.h>

#define SEQ_LEN 256
#define HIDDEN  2048
#define CLASSES 10
#define BATCH   128
#define NWG     256
#define WG_THREADS 512
#define STEPS   (SEQ_LEN - 1)
#define KTILES  64            // 2048 / 32
#define LDS_WH  131072
#define LDS_ALL (LDS_WH + 4096)

typedef __attribute__((ext_vector_type(8))) short  bf16x8;
typedef __attribute__((ext_vector_type(8))) unsigned short u16x8;
typedef __attribute__((ext_vector_type(4))) float  f32x4;
typedef __attribute__((ext_vector_type(4))) unsigned int u32x4;

// ---- workspace layout (bytes) ----
#define WHP_OFF  0
#define HB_OFF   33554432UL                    // 4 x 512 KB rotating h buffers, layout h[cb][row][u]
#define HF_OFF   (HB_OFF + 4UL * 524288UL)     // fp32 h_final [128][2048]
#define BAR_OFF  (HF_OFF + 1048576UL)
// bar layout (dwords):
//   [0..255]          arrival slot per WG (posted stores; leader L polls [32L..32L+32))
//   [512 + 16*L]      done[L], L=0..7 (64B apart)
//   [1024 + 16*j]     release line j, j=0..31 (64B apart; WG polls j = W & 31)

__device__ __forceinline__ unsigned short f2bf(float f) {
    unsigned int u = __float_as_uint(f);
    return (unsigned short)((u + 0x7FFFu + ((u >> 16) & 1u)) >> 16);
}
__device__ __forceinline__ float sigm(float z)  { return 1.0f / (1.0f + __expf(-z)); }
__device__ __forceinline__ float tanh_f(float z){ return 2.0f / (1.0f + __expf(-2.0f * z)) - 1.0f; }

__device__ __forceinline__ unsigned int aload(const unsigned int* p) {
    return __hip_atomic_load(p, __ATOMIC_RELAXED, __HIP_MEMORY_SCOPE_AGENT);
}
__device__ __forceinline__ void astore(unsigned int* p, unsigned int v) {
    __hip_atomic_store(p, v, __ATOMIC_RELAXED, __HIP_MEMORY_SCOPE_AGENT);
}

// Pack Wh [2048][8192] fp32 -> bf16 in exact MFMA B-fragment order (see R1 notes).
__global__ void lstm_pack_kernel(const float* __restrict__ Wh,
                                 unsigned short* __restrict__ whp,
                                 unsigned short* __restrict__ hbufs,
                                 unsigned int* __restrict__ bar) {
    int chunk = blockIdx.x * 256 + threadIdx.x;     // 2,097,152 chunks total
    int lane = chunk & 63;
    int nt   = (chunk >> 6) & 1;
    int kt   = (chunk >> 7) & 63;
    int W    = chunk >> 13;
    int q = lane >> 4, l16 = lane & 15;
    int c32  = nt * 16 + l16;
    int gate = c32 >> 3, u = c32 & 7;
    int n    = gate * 2048 + W * 8 + u;
    int k0   = kt * 32 + q * 8;
    u16x8 frag;
    #pragma unroll
    for (int j = 0; j < 8; ++j)
        frag[j] = f2bf(Wh[(size_t)(k0 + j) * 8192 + n]);
    ((u16x8*)whp)[chunk] = frag;

    if (chunk < 32768) ((u32x4*)hbufs)[chunk] = (u32x4){0, 0, 0, 0};   // buf0: h(0)=0
    if (chunk < 2048) bar[chunk] = 0u;                                 // barrier words
}

// Contention-free monotonic barrier (phase = t+1, never reset).
// h stores are sc1 write-through, drained by the first __syncthreads before the
// arrival store -> release ordering with no wbl2. Acquire inv only when do_inv.
__device__ __forceinline__ void grid_barrier(unsigned int* bar, unsigned int phase,
                                             bool do_inv, int W) {
    __syncthreads();   // drain sc1 h stores to the coherence point
    if (threadIdx.x < 64) {
        const int lane = threadIdx.x;
        if (lane == 0) astore(&bar[W], phase);                 // arrival
        if (W < 8) {
            unsigned int* sl = &bar[W * 32 + (lane & 31)];
            while (!__all((int)(aload(sl) >= phase)))
                __builtin_amdgcn_s_sleep(1);
            if (lane == 0) astore(&bar[512 + 16 * W], phase);  // done[W]
            if (W == 0) {
                unsigned int* dn = &bar[512 + 16 * (lane & 7)];
                while (!__all((int)(aload(dn) >= phase)))
                    __builtin_amdgcn_s_sleep(1);
                if (lane < 32) astore(&bar[1024 + 16 * lane], phase);  // broadcast
            }
        }
        if (lane == 0 && W != 0) {
            unsigned int* rl = &bar[1024 + 16 * (W & 31)];
            while (aload(rl) < phase)
                __builtin_amdgcn_s_sleep(1);
        }
        if (do_inv)
            __builtin_amdgcn_fence(__ATOMIC_ACQUIRE, "agent");   // buffer_inv (L1+L2)
    }
    __syncthreads();
}

__global__ __launch_bounds__(WG_THREADS, 2) void lstm_persist(
    const float* __restrict__ x,  const float* __restrict__ Wx,
    const float* __restrict__ b,  const float* __restrict__ Wph,
    const float* __restrict__ bp, const unsigned short* __restrict__ whp,
    unsigned short* hbufs, float* hfin,
    unsigned int* bar, float* out)
{
    extern __shared__ char lds[];
    const int tid = threadIdx.x;
    const int W   = blockIdx.x;

    // stage this WG's Wh slice (128 KB) into LDS
    {
        const u32x4* src = (const u32x4*)whp + (size_t)W * 8192;
        u32x4* dst = (u32x4*)lds;
        for (int i = tid; i < 8192; i += WG_THREADS) dst[i] = src[i];
    }
    unsigned short* hstage = (unsigned short*)(lds + LDS_WH);   // [row][u] bf16, 2 KB
    __syncthreads();

    const int lane = tid & 63;
    const int wv   = tid >> 6;          // wave 0..7 -> M-tile
    const int q    = lane >> 4;         // quad 0..3
    const int l16  = lane & 15;
    const int s    = (lane >> 3) & 1;   // 0: holds (g,f); 1: holds (i,o)
    const int u    = lane & 7;          // hidden unit within slice
    const int rowA = wv * 16 + l16;     // A row this lane loads
    const int row0 = wv * 16 + q * 4;   // C/D rows row0..row0+3
    const int colh = W * 8 + u;         // global hidden index this lane updates

    const int n0 = ((l16) >> 3) * 2048 + W * 8 + (l16 & 7);
    const int n1 = ((16 + l16) >> 3) * 2048 + W * 8 + ((16 + l16) & 7);
    const float wx0 = Wx[n0], bb0 = b[n0];
    const float wx1 = Wx[n1], bb1 = b[n1];

    // A-fragment address in the blocked layout h[cb][row][u]:
    // lane (q,row) reads h[kt*4+q][rowA][0..7] = one contiguous bf16x8 at
    // index (kt*4+q)*128+rowA; a quad's 16 lanes span 256 B contiguous.
    const int abase = q * 128 + rowA;

    float c_state[4] = {0.f, 0.f, 0.f, 0.f};

    for (int t = 0; t < STEPS; ++t) {
        unsigned short* hcur  = hbufs + (size_t)(t & 3) * 262144;        // elements
        unsigned short* hnext = hbufs + (size_t)((t + 1) & 3) * 262144;

        const bf16x8* hc8 = (const bf16x8*)hcur;
        const char* lp = lds + lane * 16;

        float xv[4];
        #pragma unroll
        for (int r = 0; r < 4; ++r) xv[r] = x[(row0 + r) * SEQ_LEN + t];

        f32x4 acc0 = {0.f, 0.f, 0.f, 0.f};
        f32x4 acc1 = {0.f, 0.f, 0.f, 0.f};
        bf16x8 a_cur = hc8[abase];
        #pragma unroll 8
        for (int kt = 0; kt < KTILES; ++kt) {
            bf16x8 a_nxt = (kt < KTILES - 1) ? hc8[abase + (kt + 1) * 512] : a_cur;
            bf16x8 b0 = *(const bf16x8*)(lp + (kt * 2 + 0) * 1024);
            bf16x8 b1 = *(const bf16x8*)(lp + (kt * 2 + 1) * 1024);
            acc0 = __builtin_amdgcn_mfma_f32_16x16x32_bf16(a_cur, b0, acc0, 0, 0, 0);
            acc1 = __builtin_amdgcn_mfma_f32_16x16x32_bf16(a_cur, b1, acc1, 0, 0, 0);
            a_cur = a_nxt;
        }

        const bool last = (t == STEPS - 1);
        #pragma unroll
        for (int r = 0; r < 4; ++r) {
            float z0 = acc0[r] + xv[r] * wx0 + bb0;
            float z1 = acc1[r] + xv[r] * wx1 + bb1;
            float p0 = __shfl_xor(z0, 8, 64);
            float p1 = __shfl_xor(z1, 8, 64);
            float zg = s ? p0 : z0;
            float zi = s ? z0 : p0;
            float zf = s ? p1 : z1;
            float zo = s ? z1 : p1;
            float cn = tanh_f(zg) * sigm(zi) + c_state[r] * sigm(zf);
            c_state[r] = cn;
            float h = tanh_f(cn) * sigm(zo);
            if (s == 0) {
                hstage[(row0 + r) * 8 + u] = f2bf(h);      // stage into LDS
                if (last)
                    __hip_atomic_store(&hfin[(row0 + r) * HIDDEN + colh], h,
                                       __ATOMIC_RELAXED, __HIP_MEMORY_SCOPE_AGENT);
            }
        }
        __syncthreads();   // hstage complete
        // cooperative coalesced write of this WG's 2 KB h-block (1 dword/thread)
        astore(&((unsigned int*)hnext)[W * 512 + tid],
               ((const unsigned int*)hstage)[tid]);
        // inv every 4th barrier (stale L2 age <= 4 with the 4-buffer rotation);
        // t==254 (phase 2) also covers the hfin handoff to the cached epilogue.
        grid_barrier(bar, (unsigned int)(t + 1), (t & 3) == 2 || last, W);
    }

    // ---- classifier + softmax epilogue: WG b handles batch row b ----
    if (W < BATCH) {
        float part[CLASSES];
        #pragma unroll
        for (int c = 0; c < CLASSES; ++c) part[c] = 0.f;
        for (int k = tid; k < HIDDEN; k += WG_THREADS) {
            float hv = hfin[W * HIDDEN + k];
            #pragma unroll
            for (int c = 0; c < CLASSES; ++c) part[c] += hv * Wph[k * CLASSES + c];
        }
        #pragma unroll
        for (int c = 0; c < CLASSES; ++c)
            for (int off = 32; off > 0; off >>= 1)
                part[c] += __shfl_xor(part[c], off, 64);
        float* red = (float*)(lds + LDS_WH);
        __syncthreads();
        if (lane == 0)
            for (int c = 0; c < CLASSES; ++c) red[wv * CLASSES + c] = part[c];
        __syncthreads();
        if (tid == 0) {
            float lg[CLASSES];
            for (int c = 0; c < CLASSES; ++c) {
                float sm = bp[c];
                for (int w8 = 0; w8 < 8; ++w8) sm += red[w8 * CLASSES + c];
                lg[c] = sm;
            }
            float mx = lg[0];
            for (int c = 1; c < CLASSES; ++c) mx = fmaxf(mx, lg[c]);
            float se = 0.f;
            for (int c = 0; c < CLASSES; ++c) { lg[c] = __expf(lg[c] - mx); se += lg[c]; }
            float inv = 1.0f / se;
            for (int c = 0; c < CLASSES; ++c) out[W * CLASSES + c] = lg[c] * inv;
        }
    }
}

extern "C" void kernel_launch(void* const* d_in, const int* in_sizes, int n_in,
                              void* d_out, int out_size, void* d_ws, size_t ws_size,
                              hipStream_t stream) {
    const float* x   = (const float*)d_in[0];
    const float* Wx  = (const float*)d_in[1];
    const float* Wh  = (const float*)d_in[2];
    const float* b   = (const float*)d_in[3];
    const float* Wph = (const float*)d_in[4];
    const float* bp  = (const float*)d_in[5];
    float* out = (float*)d_out;

    char* ws = (char*)d_ws;
    unsigned short* whp  = (unsigned short*)(ws + WHP_OFF);
    unsigned short* hbufs= (unsigned short*)(ws + HB_OFF);
    float*          hfin = (float*)(ws + HF_OFF);
    unsigned int*   bar  = (unsigned int*)(ws + BAR_OFF);

    hipFuncSetAttribute((const void*)lstm_persist,
                        hipFuncAttributeMaxDynamicSharedMemorySize, LDS_ALL);

    lstm_pack_kernel<<<8192, 256, 0, stream>>>(Wh, whp, hbufs, bar);
    lstm_persist<<<NWG, WG_THREADS, LDS_ALL, stream>>>(x, Wx, b, Wph, bp,
                                                       whp, hbufs, hfin, bar, out);
}